// Round 6
// baseline (177.506 us; speedup 1.0000x reference)
//
#include <hip/hip_runtime.h>
#include <hip/hip_bf16.h>

#define NB   4
#define NC   2
#define NS   4096
#define NOUT 512
#define UPAD 80          // stored u-stride in workspace (u<65 consumed)
#define KCN  32          // split-K slices
#define KC   128         // 4096 / KCN
#define NBLK 512         // NB * 4 * KCN / ... = 4b * 4ot * 32kc
#define PART_BYTES ((size_t)KCN * NB * NOUT * UPAD * 2)   // 10,485,760
#define CNT_OFF    PART_BYTES

typedef short  short8_t  __attribute__((ext_vector_type(8)));
typedef short  short4_t  __attribute__((ext_vector_type(4)));
typedef float  float16_t __attribute__((ext_vector_type(16)));

__device__ __forceinline__ short bf16s(float f) {
    union { __hip_bfloat16 b; short s; } u;
    u.b = __float2bfloat16(f);   // RNE
    return u.s;
}
__device__ __forceinline__ float s2f(unsigned short s) {
    union { unsigned int u; float f; } v;
    v.u = ((unsigned int)s) << 16;
    return v.f;
}

// ---------------------------------------------------------------------------
// Single-dispatch fused kernel. 512 blocks, all co-resident (LDS 41.2 KB ->
// 3 blocks/CU capacity = 768 >= 512), so the flag barrier cannot deadlock.
//   Phase 1 (validated R2-R5 structure, KCN=32): block (kc,ot,b) computes a
//     128o x 96u x 128k bf16-MFMA tile, stores bf16 partials to ws.
//   Barrier: release-fence + atomicAdd; spin to NBLK; acquire-fence.
//   Phase 2 (validated): each block reduces + epilogues 4 (b,o) pairs.
// ---------------------------------------------------------------------------
__global__ __launch_bounds__(256, 2)
void fused_onelaunch(const float* __restrict__ x,
                     const float* __restrict__ stft_w,
                     const float* __restrict__ conv_w,
                     const float* __restrict__ conv_b,
                     float* __restrict__ out,
                     unsigned short* __restrict__ hpart,
                     unsigned int* __restrict__ cnt)
{
    constexpr int XSZ     = KC + 56;   // shifted-copy coverage (R5 note)
    constexpr int ASTRIDE = KC + 8;    // shorts; 16B-aligned rows

    __shared__ __align__(16) short aS[128 * ASTRIDE];  // 34.8 KB
    __shared__ __align__(16) short xS[16][XSZ];        //  5.9 KB
    __shared__ float HsA[65], HsB[65];

    const int blk = blockIdx.x;
    const int kc  = blk & 31;
    const int ot  = (blk >> 5) & 3;
    const int b   = blk >> 7;

    const int K0 = kc * KC;
    const int c  = K0 >> 11;
    const int tb = K0 & 2047;
    const int tid = threadIdx.x;

    // ---- phase 1: stage B (xe/xo + 8 shifted copies each) ----
    const float* xc = x + (size_t)(b * NC + c) * NS;
    for (int i = tid; i < XSZ; i += 256) {
        int ge = (tb + i) * 2;
        float fe = (ge     < NS) ? xc[ge]     : 0.0f;
        float fo = (ge + 1 < NS) ? xc[ge + 1] : 0.0f;
        short se = bf16s(fe), so = bf16s(fo);
        #pragma unroll
        for (int r = 0; r < 8; ++r) {
            int j = i - r;
            if (j >= 0) { xS[r][j] = se; xS[8 + r][j] = so; }
        }
    }

    // ---- phase 1: stage A coalesced, bf16 in LDS ----
    {
        const int rr = tid >> 5;
        const int cc = (tid & 31) * 4;
        const float* wbase = conv_w + (size_t)(ot * 128) * 4096 + K0;
        #pragma unroll
        for (int it = 0; it < 16; ++it) {
            int row = it * 8 + rr;
            float4 v = *(const float4*)(wbase + (size_t)row * 4096 + cc);
            short4_t p = { bf16s(v.x), bf16s(v.y), bf16s(v.z), bf16s(v.w) };
            *(short4_t*)&aS[row * ASTRIDE + cc] = p;
        }
    }
    __syncthreads();

    const int wave = tid >> 6;
    const int lane = tid & 63;
    const int l31  = lane & 31;
    const int q    = lane >> 5;

    const short* arow = &aS[(wave * 32 + l31) * ASTRIDE];

    float16_t acc[3];
    #pragma unroll
    for (int nt = 0; nt < 3; ++nt)
        #pragma unroll
        for (int e = 0; e < 16; ++e) acc[nt][e] = 0.0f;

    int arr[3], hb[3];
    #pragma unroll
    for (int nt = 0; nt < 3; ++nt) {
        int uu = nt * 32 + l31;
        int h  = uu >> 1;
        arr[nt] = (uu & 1) * 8 + (h & 7);
        hb[nt]  = h & ~7;
    }

    #pragma unroll
    for (int step = 0; step < KC / 16; ++step) {
        const int kl = step * 16 + q * 8;
        short8_t af = *(const short8_t*)(arow + kl);
        #pragma unroll
        for (int nt = 0; nt < 3; ++nt) {
            short8_t bf = *(const short8_t*)&xS[arr[nt]][kl + hb[nt]];
            acc[nt] = __builtin_amdgcn_mfma_f32_32x32x16_bf16(af, bf, acc[nt], 0, 0, 0);
        }
    }

    // D layout (validated): col=lane&31 (u), row=(reg&3)+8*(reg>>2)+4*q
    unsigned short* hp = hpart + (size_t)(kc * NB + b) * NOUT * UPAD;
    #pragma unroll
    for (int nt = 0; nt < 3; ++nt) {
        int uu = nt * 32 + l31;
        if (uu < UPAD) {
            #pragma unroll
            for (int reg = 0; reg < 16; ++reg) {
                int row = (reg & 3) + 8 * (reg >> 2) + 4 * q;
                int o   = ot * 128 + wave * 32 + row;
                hp[(size_t)o * UPAD + uu] = (unsigned short)bf16s(acc[nt][reg]);
            }
        }
    }

    // ---- device-scope barrier (stream-k fixup pattern) ----
    __syncthreads();                       // drains this block's stores (vmcnt)
    if (tid == 0) {
        __threadfence();                   // agent release: wbl2 this XCD's L2
        atomicAdd(cnt, 1u);
        while (__hip_atomic_load(cnt, __ATOMIC_ACQUIRE,
                                 __HIP_MEMORY_SCOPE_AGENT) < NBLK)
            __builtin_amdgcn_s_sleep(2);
    }
    __syncthreads();
    __threadfence();                       // agent acquire: inv stale L1/L2 lines

    // ---- phase 2: 4 (b,o) pairs per block ----
    constexpr int HALF = KCN / 2;
    const size_t slice = (size_t)NB * NOUT * UPAD;

    for (int i = 0; i < 4; ++i) {
        const int P  = (blk << 2) + i;
        const int b2 = P >> 9;
        const int o2 = P & 511;

        if (tid < 65) {                        // slices [0, HALF)
            const unsigned short* hp0 = hpart + ((size_t)b2 * NOUT + o2) * UPAD + tid;
            float h = 0.0f;
            #pragma unroll
            for (int s = 0; s < HALF; ++s) h += s2f(hp0[(size_t)s * slice]);
            HsA[tid] = h;
        } else if (tid >= 128 && tid < 193) {  // slices [HALF, KCN)
            const unsigned short* hp0 = hpart + ((size_t)b2 * NOUT + o2) * UPAD
                                      + (tid - 128) + (size_t)HALF * slice;
            float h = 0.0f;
            #pragma unroll
            for (int s = 0; s < KCN - HALF; ++s) h += s2f(hp0[(size_t)s * slice]);
            HsB[tid - 128] = h;
        }
        __syncthreads();

        const float bias = conv_b[o2];
        float* ob = out + (size_t)(b2 * NOUT + o2) * NS;
        #pragma unroll
        for (int it = 0; it < 4; ++it) {
            int s4 = (it * 256 + tid) * 4;
            int r  = s4 >> 11;
            int qq = s4 & 2047;
            int m  = qq >> 5;
            int l  = qq & 31;
            float h = HsA[r + m] + HsB[r + m];
            float v0 = fmaf(stft_w[(l + 0) * 64 + m], h, bias);
            float v1 = fmaf(stft_w[(l + 1) * 64 + m], h, bias);
            float v2 = fmaf(stft_w[(l + 2) * 64 + m], h, bias);
            float v3 = fmaf(stft_w[(l + 3) * 64 + m], h, bias);
            float4 res;
            res.x = v0 > 0.0f ? v0 : 0.0f;
            res.y = v1 > 0.0f ? v1 : 0.0f;
            res.z = v2 > 0.0f ? v2 : 0.0f;
            res.w = v3 > 0.0f ? v3 : 0.0f;
            *(float4*)(ob + s4) = res;
        }
        __syncthreads();                   // Hs reused next iteration
    }
}

// ---------------------------------------------------------------------------
// Fallback (ws too small — never expected): validated R1 fused kernel.
// ---------------------------------------------------------------------------
__device__ __forceinline__ int swz(int i) { return i + (i >> 5); }

__global__ __launch_bounds__(256, 3)
void fused_cnn(const float* __restrict__ x,
               const float* __restrict__ stft_w,
               const float* __restrict__ conv_w,
               const float* __restrict__ conv_b,
               float* __restrict__ out)
{
    __shared__ float xs[2 * 4290];
    __shared__ float ws_[4224];
    __shared__ float Hs[65];

    const int tid = threadIdx.x;
    const int bid = blockIdx.x;
    const int b = bid >> 9;
    const int o = bid & 511;

    for (int c = 0; c < NC; ++c) {
        const float* xb = x + (size_t)(b * NC + c) * NS;
        float* dst = xs + c * 4290;
        #pragma unroll
        for (int it = 0; it < 4; ++it) {
            int i0 = (it * 256 + tid) * 4;
            float4 v = *(const float4*)(xb + i0);
            dst[swz(i0 + 0)] = v.x; dst[swz(i0 + 1)] = v.y;
            dst[swz(i0 + 2)] = v.z; dst[swz(i0 + 3)] = v.w;
        }
        if (tid < 64) dst[swz(4096 + tid)] = 0.0f;
    }
    {
        const float* wrow = conv_w + (size_t)o * 4096;
        #pragma unroll
        for (int it = 0; it < 4; ++it) {
            int i0 = (it * 256 + tid) * 4;
            float4 v = *(const float4*)(wrow + i0);
            ws_[swz(i0 + 0)] = v.x; ws_[swz(i0 + 1)] = v.y;
            ws_[swz(i0 + 2)] = v.z; ws_[swz(i0 + 3)] = v.w;
        }
    }
    __syncthreads();

    const int wave = tid >> 6;
    const int lane = tid & 63;
    const int u0 = wave << 4;

    float acc[17];
    #pragma unroll
    for (int i = 0; i < 17; ++i) acc[i] = 0.0f;

    for (int g = 0; g < 8; ++g) {
        int G = lane + (g << 6);
        int c = G >> 8;
        int t0 = (G & 255) << 3;
        int wb = c * 2048 + t0;
        float w[8];
        #pragma unroll
        for (int j = 0; j < 8; ++j) w[j] = ws_[swz(wb + j)];
        const float* xcs = xs + c * 4290;
        int xb0 = 2 * t0 + u0;
        #pragma unroll
        for (int d = 0; d <= 30; ++d) {
            float xv = xcs[swz(xb0 + d)];
            #pragma unroll
            for (int j = 0; j < 8; ++j) {
                int uu = d - 2 * j;
                if (uu >= 0 && uu < 17) acc[uu] += w[j] * xv;
            }
        }
    }
    #pragma unroll
    for (int uu = 0; uu < 17; ++uu) {
        float v = acc[uu];
        #pragma unroll
        for (int off = 1; off < 64; off <<= 1) v += __shfl_xor(v, off, 64);
        acc[uu] = v;
    }
    if (lane == 0)
        #pragma unroll
        for (int uu = 0; uu < 17; ++uu)
            if (uu < 16 || wave == 3) Hs[u0 + uu] = acc[uu];
    __syncthreads();

    const float bias = conv_b[o];
    float* ob = out + (size_t)(b * NOUT + o) * NS;
    #pragma unroll
    for (int it = 0; it < 4; ++it) {
        int s4 = (it * 256 + tid) * 4;
        int r = s4 >> 11;
        int qq = s4 & 2047;
        int m = qq >> 5;
        int l = qq & 31;
        float h = Hs[r + m];
        float v0 = fmaf(stft_w[(l + 0) * 64 + m], h, bias);
        float v1 = fmaf(stft_w[(l + 1) * 64 + m], h, bias);
        float v2 = fmaf(stft_w[(l + 2) * 64 + m], h, bias);
        float v3 = fmaf(stft_w[(l + 3) * 64 + m], h, bias);
        float4 res;
        res.x = v0 > 0.0f ? v0 : 0.0f;
        res.y = v1 > 0.0f ? v1 : 0.0f;
        res.z = v2 > 0.0f ? v2 : 0.0f;
        res.w = v3 > 0.0f ? v3 : 0.0f;
        *(float4*)(ob + s4) = res;
    }
}

// ---------------------------------------------------------------------------
extern "C" void kernel_launch(void* const* d_in, const int* in_sizes, int n_in,
                              void* d_out, int out_size, void* d_ws, size_t ws_size,
                              hipStream_t stream) {
    const float* x      = (const float*)d_in[0];
    const float* stft_w = (const float*)d_in[1];
    const float* conv_w = (const float*)d_in[2];
    const float* conv_b = (const float*)d_in[3];
    float* out = (float*)d_out;

    if (ws_size >= CNT_OFF + 64) {
        unsigned short* hpart = (unsigned short*)d_ws;
        unsigned int*   cnt   = (unsigned int*)((char*)d_ws + CNT_OFF);
        hipMemsetAsync((void*)cnt, 0, 4, stream);   // ws is poisoned 0xAA each call
        fused_onelaunch<<<dim3(NBLK), dim3(256), 0, stream>>>(
            x, stft_w, conv_w, conv_b, out, hpart, cnt);
    } else {
        fused_cnn<<<dim3(NB * NOUT), dim3(256), 0, stream>>>(
            x, stft_w, conv_w, conv_b, out);
    }
}

// Round 7
// 117.160 us; speedup vs baseline: 1.5151x; 1.5151x over previous
//
#include <hip/hip_runtime.h>
#include <hip/hip_bf16.h>

#define NB   4
#define NC   2
#define NS   4096
#define NOUT 512
#define UPAD 80          // stored u-stride in workspace (u<65 consumed)
#define KCN  32          // split-K slices
#define KC   128         // 4096 / KCN
#define NBLK 512         // 4b * 4ot * 32kc
#define PART_BYTES ((size_t)KCN * NB * NOUT * UPAD * 2)   // 10,485,760
#define CNT_OFF    PART_BYTES

typedef short  short8_t  __attribute__((ext_vector_type(8)));
typedef short  short4_t  __attribute__((ext_vector_type(4)));
typedef float  float16_t __attribute__((ext_vector_type(16)));

__device__ __forceinline__ short bf16s(float f) {
    union { __hip_bfloat16 b; short s; } u;
    u.b = __float2bfloat16(f);   // RNE
    return u.s;
}
__device__ __forceinline__ float s2f(unsigned short s) {
    union { unsigned int u; float f; } v;
    v.u = ((unsigned int)s) << 16;
    return v.f;
}

// ---------------------------------------------------------------------------
// Single-dispatch fused kernel, fence-free device barrier.
//   Phase 1 (validated R2-R6): block (kc,ot,b) computes a 128o x 96u x 128k
//     bf16-MFMA tile; partials stored with SYSTEM-scope bypass stores
//     (sc0 sc1 -> MALL/LLC; no dirty L2 lines, so no release wbl2 needed).
//   Barrier: __syncthreads (drains vmcnt -> stores LLC-visible), tid0 does
//     relaxed SYSTEM atomicAdd + relaxed SYSTEM poll (cache-bypassing load:
//     always fresh, NO buffer_inv side effect -> no fence storm, no livelock).
//   Phase 2 (validated R6): plain loads (consumer L2 clean-miss -> LLC hit,
//     fresh by construction), 4 (b,o) pairs per block.
//   Co-residency: __launch_bounds__(256,2) -> 2 blocks/CU x 256 CU = 512 = grid.
// ---------------------------------------------------------------------------
__global__ __launch_bounds__(256, 2)
void fused_onelaunch(const float* __restrict__ x,
                     const float* __restrict__ stft_w,
                     const float* __restrict__ conv_w,
                     const float* __restrict__ conv_b,
                     float* __restrict__ out,
                     unsigned short* __restrict__ hpart,
                     unsigned int* __restrict__ cnt)
{
    constexpr int XSZ     = KC + 56;   // shifted-copy coverage (R5 note)
    constexpr int ASTRIDE = KC + 8;    // shorts; 16B-aligned rows

    __shared__ __align__(16) short aS[128 * ASTRIDE];  // 34.8 KB
    __shared__ __align__(16) short xS[16][XSZ];        //  5.9 KB
    __shared__ float HsA[65], HsB[65];

    const int blk = blockIdx.x;
    const int kc  = blk & 31;
    const int ot  = (blk >> 5) & 3;
    const int b   = blk >> 7;

    const int K0 = kc * KC;
    const int c  = K0 >> 11;
    const int tb = K0 & 2047;
    const int tid = threadIdx.x;

    // ---- phase 1: stage B (xe/xo + 8 shifted copies each) ----
    const float* xc = x + (size_t)(b * NC + c) * NS;
    for (int i = tid; i < XSZ; i += 256) {
        int ge = (tb + i) * 2;
        float fe = (ge     < NS) ? xc[ge]     : 0.0f;
        float fo = (ge + 1 < NS) ? xc[ge + 1] : 0.0f;
        short se = bf16s(fe), so = bf16s(fo);
        #pragma unroll
        for (int r = 0; r < 8; ++r) {
            int j = i - r;
            if (j >= 0) { xS[r][j] = se; xS[8 + r][j] = so; }
        }
    }

    // ---- phase 1: stage A coalesced, bf16 in LDS ----
    {
        const int rr = tid >> 5;
        const int cc = (tid & 31) * 4;
        const float* wbase = conv_w + (size_t)(ot * 128) * 4096 + K0;
        #pragma unroll
        for (int it = 0; it < 16; ++it) {
            int row = it * 8 + rr;
            float4 v = *(const float4*)(wbase + (size_t)row * 4096 + cc);
            short4_t p = { bf16s(v.x), bf16s(v.y), bf16s(v.z), bf16s(v.w) };
            *(short4_t*)&aS[row * ASTRIDE + cc] = p;
        }
    }
    __syncthreads();

    const int wave = tid >> 6;
    const int lane = tid & 63;
    const int l31  = lane & 31;
    const int q    = lane >> 5;

    const short* arow = &aS[(wave * 32 + l31) * ASTRIDE];

    float16_t acc[3];
    #pragma unroll
    for (int nt = 0; nt < 3; ++nt)
        #pragma unroll
        for (int e = 0; e < 16; ++e) acc[nt][e] = 0.0f;

    int arr[3], hb[3];
    #pragma unroll
    for (int nt = 0; nt < 3; ++nt) {
        int uu = nt * 32 + l31;
        int h  = uu >> 1;
        arr[nt] = (uu & 1) * 8 + (h & 7);
        hb[nt]  = h & ~7;
    }

    #pragma unroll
    for (int step = 0; step < KC / 16; ++step) {
        const int kl = step * 16 + q * 8;
        short8_t af = *(const short8_t*)(arow + kl);
        #pragma unroll
        for (int nt = 0; nt < 3; ++nt) {
            short8_t bf = *(const short8_t*)&xS[arr[nt]][kl + hb[nt]];
            acc[nt] = __builtin_amdgcn_mfma_f32_32x32x16_bf16(af, bf, acc[nt], 0, 0, 0);
        }
    }

    // D layout (validated): col=lane&31 (u), row=(reg&3)+8*(reg>>2)+4*q
    // SYSTEM-scope relaxed stores: sc0 sc1 -> bypass L1/L2, land in MALL/LLC.
    unsigned short* hp = hpart + (size_t)(kc * NB + b) * NOUT * UPAD;
    #pragma unroll
    for (int nt = 0; nt < 3; ++nt) {
        int uu = nt * 32 + l31;
        if (uu < UPAD) {
            #pragma unroll
            for (int reg = 0; reg < 16; ++reg) {
                int row = (reg & 3) + 8 * (reg >> 2) + 4 * q;
                int o   = ot * 128 + wave * 32 + row;
                __hip_atomic_store(&hp[(size_t)o * UPAD + uu],
                                   (unsigned short)bf16s(acc[nt][reg]),
                                   __ATOMIC_RELAXED, __HIP_MEMORY_SCOPE_SYSTEM);
            }
        }
    }

    // ---- fence-free device barrier ----
    __syncthreads();   // every wave drains its vmcnt -> bypass stores at LLC
    if (tid == 0) {
        __hip_atomic_fetch_add(cnt, 1u, __ATOMIC_RELAXED,
                               __HIP_MEMORY_SCOPE_SYSTEM);
        while (__hip_atomic_load(cnt, __ATOMIC_RELAXED,
                                 __HIP_MEMORY_SCOPE_SYSTEM) < NBLK)
            __builtin_amdgcn_s_sleep(8);
    }
    __syncthreads();

    // ---- phase 2: 4 (b,o) pairs per block (plain loads: LLC-fresh) ----
    constexpr int HALF = KCN / 2;
    const size_t slice = (size_t)NB * NOUT * UPAD;

    for (int i = 0; i < 4; ++i) {
        const int P  = (blk << 2) + i;
        const int b2 = P >> 9;
        const int o2 = P & 511;

        if (tid < 65) {                        // slices [0, HALF)
            const unsigned short* hp0 = hpart + ((size_t)b2 * NOUT + o2) * UPAD + tid;
            float h = 0.0f;
            #pragma unroll
            for (int s = 0; s < HALF; ++s) h += s2f(hp0[(size_t)s * slice]);
            HsA[tid] = h;
        } else if (tid >= 128 && tid < 193) {  // slices [HALF, KCN)
            const unsigned short* hp0 = hpart + ((size_t)b2 * NOUT + o2) * UPAD
                                      + (tid - 128) + (size_t)HALF * slice;
            float h = 0.0f;
            #pragma unroll
            for (int s = 0; s < KCN - HALF; ++s) h += s2f(hp0[(size_t)s * slice]);
            HsB[tid - 128] = h;
        }
        __syncthreads();

        const float bias = conv_b[o2];
        float* ob = out + (size_t)(b2 * NOUT + o2) * NS;
        #pragma unroll
        for (int it = 0; it < 4; ++it) {
            int s4 = (it * 256 + tid) * 4;
            int r  = s4 >> 11;
            int qq = s4 & 2047;
            int m  = qq >> 5;
            int l  = qq & 31;
            float h = HsA[r + m] + HsB[r + m];
            float v0 = fmaf(stft_w[(l + 0) * 64 + m], h, bias);
            float v1 = fmaf(stft_w[(l + 1) * 64 + m], h, bias);
            float v2 = fmaf(stft_w[(l + 2) * 64 + m], h, bias);
            float v3 = fmaf(stft_w[(l + 3) * 64 + m], h, bias);
            float4 res;
            res.x = v0 > 0.0f ? v0 : 0.0f;
            res.y = v1 > 0.0f ? v1 : 0.0f;
            res.z = v2 > 0.0f ? v2 : 0.0f;
            res.w = v3 > 0.0f ? v3 : 0.0f;
            *(float4*)(ob + s4) = res;
        }
        __syncthreads();                   // Hs reused next iteration
    }
}

// ---------------------------------------------------------------------------
// Fallback (ws too small — never expected): validated R1 fused kernel.
// ---------------------------------------------------------------------------
__device__ __forceinline__ int swz(int i) { return i + (i >> 5); }

__global__ __launch_bounds__(256, 3)
void fused_cnn(const float* __restrict__ x,
               const float* __restrict__ stft_w,
               const float* __restrict__ conv_w,
               const float* __restrict__ conv_b,
               float* __restrict__ out)
{
    __shared__ float xs[2 * 4290];
    __shared__ float ws_[4224];
    __shared__ float Hs[65];

    const int tid = threadIdx.x;
    const int bid = blockIdx.x;
    const int b = bid >> 9;
    const int o = bid & 511;

    for (int c = 0; c < NC; ++c) {
        const float* xb = x + (size_t)(b * NC + c) * NS;
        float* dst = xs + c * 4290;
        #pragma unroll
        for (int it = 0; it < 4; ++it) {
            int i0 = (it * 256 + tid) * 4;
            float4 v = *(const float4*)(xb + i0);
            dst[swz(i0 + 0)] = v.x; dst[swz(i0 + 1)] = v.y;
            dst[swz(i0 + 2)] = v.z; dst[swz(i0 + 3)] = v.w;
        }
        if (tid < 64) dst[swz(4096 + tid)] = 0.0f;
    }
    {
        const float* wrow = conv_w + (size_t)o * 4096;
        #pragma unroll
        for (int it = 0; it < 4; ++it) {
            int i0 = (it * 256 + tid) * 4;
            float4 v = *(const float4*)(wrow + i0);
            ws_[swz(i0 + 0)] = v.x; ws_[swz(i0 + 1)] = v.y;
            ws_[swz(i0 + 2)] = v.z; ws_[swz(i0 + 3)] = v.w;
        }
    }
    __syncthreads();

    const int wave = tid >> 6;
    const int lane = tid & 63;
    const int u0 = wave << 4;

    float acc[17];
    #pragma unroll
    for (int i = 0; i < 17; ++i) acc[i] = 0.0f;

    for (int g = 0; g < 8; ++g) {
        int G = lane + (g << 6);
        int c = G >> 8;
        int t0 = (G & 255) << 3;
        int wb = c * 2048 + t0;
        float w[8];
        #pragma unroll
        for (int j = 0; j < 8; ++j) w[j] = ws_[swz(wb + j)];
        const float* xcs = xs + c * 4290;
        int xb0 = 2 * t0 + u0;
        #pragma unroll
        for (int d = 0; d <= 30; ++d) {
            float xv = xcs[swz(xb0 + d)];
            #pragma unroll
            for (int j = 0; j < 8; ++j) {
                int uu = d - 2 * j;
                if (uu >= 0 && uu < 17) acc[uu] += w[j] * xv;
            }
        }
    }
    #pragma unroll
    for (int uu = 0; uu < 17; ++uu) {
        float v = acc[uu];
        #pragma unroll
        for (int off = 1; off < 64; off <<= 1) v += __shfl_xor(v, off, 64);
        acc[uu] = v;
    }
    if (lane == 0)
        #pragma unroll
        for (int uu = 0; uu < 17; ++uu)
            if (uu < 16 || wave == 3) Hs[u0 + uu] = acc[uu];
    __syncthreads();

    const float bias = conv_b[o];
    float* ob = out + (size_t)(b * NOUT + o) * NS;
    #pragma unroll
    for (int it = 0; it < 4; ++it) {
        int s4 = (it * 256 + tid) * 4;
        int r = s4 >> 11;
        int qq = s4 & 2047;
        int m = qq >> 5;
        int l = qq & 31;
        float h = Hs[r + m];
        float v0 = fmaf(stft_w[(l + 0) * 64 + m], h, bias);
        float v1 = fmaf(stft_w[(l + 1) * 64 + m], h, bias);
        float v2 = fmaf(stft_w[(l + 2) * 64 + m], h, bias);
        float v3 = fmaf(stft_w[(l + 3) * 64 + m], h, bias);
        float4 res;
        res.x = v0 > 0.0f ? v0 : 0.0f;
        res.y = v1 > 0.0f ? v1 : 0.0f;
        res.z = v2 > 0.0f ? v2 : 0.0f;
        res.w = v3 > 0.0f ? v3 : 0.0f;
        *(float4*)(ob + s4) = res;
    }
}

// ---------------------------------------------------------------------------
extern "C" void kernel_launch(void* const* d_in, const int* in_sizes, int n_in,
                              void* d_out, int out_size, void* d_ws, size_t ws_size,
                              hipStream_t stream) {
    const float* x      = (const float*)d_in[0];
    const float* stft_w = (const float*)d_in[1];
    const float* conv_w = (const float*)d_in[2];
    const float* conv_b = (const float*)d_in[3];
    float* out = (float*)d_out;

    if (ws_size >= CNT_OFF + 64) {
        unsigned short* hpart = (unsigned short*)d_ws;
        unsigned int*   cnt   = (unsigned int*)((char*)d_ws + CNT_OFF);
        hipMemsetAsync((void*)cnt, 0, 4, stream);   // ws is poisoned 0xAA each call
        fused_onelaunch<<<dim3(NBLK), dim3(256), 0, stream>>>(
            x, stft_w, conv_w, conv_b, out, hpart, cnt);
    } else {
        fused_cnn<<<dim3(NB * NOUT), dim3(256), 0, stream>>>(
            x, stft_w, conv_w, conv_b, out);
    }
}